// Round 14
// baseline (191.601 us; speedup 1.0000x reference)
//
#include <hip/hip_runtime.h>

// 3x3 median blur + residual, zero padding, x:(8,3,1024,1024) f32.
// Round-13 (resubmit; R13 bench was GPUAcquisitionTimeout, never ran).
// Combine R12's proven-at-ceiling structure with register reuse.
// R12 measured 384 MB logical VMEM in 61.4us = 6.25 TB/s = the m13 copy
// ceiling -> that shape (wave owns full row, 4 column-chunks, perfect 1KB
// slots, chunk-loop) saturates the vector-memory byte service rate; its
// waste is 3x redundant reads. This kernel keeps the structure and cuts
// logical bytes 384->246 MB: each wave produces 4 OUTPUT ROWS from 6 input
// rows, chunk-by-chunk double-buffered (c[2][6], all indices compile-time).
// Cross-chunk halos: lane-63 carry (left) + next-chunk lane-0 broadcast
// (right); image edges are wave-internal (lane0 chunk0 / lane63 chunk3).
// No LDS, no barriers, waves independent. Bijective XCD chunk swizzle:
// 1536 blocks, 192/XCD = exactly 3 planes -> zero cross-XCD row sharing.
// Whole grid resident: 6 blocks/CU at __launch_bounds__(256,6).

typedef float v4f __attribute__((ext_vector_type(4)));

#define S2(a,b) { float _t=fminf(a,b); (b)=fmaxf(a,b); (a)=_t; }
__device__ __forceinline__ float med3f(float a, float b, float c) {
    return fmaxf(fminf(a, b), fminf(fmaxf(a, b), c));
}

constexpr int W = 1024, H = 1024;
constexpr int RPW = 4;                    // output rows per wave
constexpr int NRW = RPW + 2;              // input rows per wave (6)

__global__ __launch_bounds__(256, 6) void median_blur_kernel(
    const float* __restrict__ xin, float* __restrict__ out)
{
    // bijective XCD-chunked remap (gridDim.x = 1536, %8==0; 192 blocks =
    // 3072 rows = exactly 3 planes per XCD -> no cross-XCD row sharing)
    const unsigned orig   = blockIdx.x;
    const unsigned chunkB = gridDim.x >> 3;
    const unsigned wg     = (orig & 7u) * chunkB + (orig >> 3);

    const int tx   = threadIdx.x;
    const int wv   = tx >> 6;                     // wave 0..3
    const int lane = tx & 63;

    const unsigned g = wg * 4u + (unsigned)wv;    // row-group id 0..6143
    const int    y0    = (int)((g & 255u) << 2);  // 0,4,...,1020 within plane
    const size_t plane = (size_t)(g >> 8) * (size_t)(H * W);
    const float* base  = xin + plane;
    float*       obase = out + plane;

    const bool top = (y0 == 0);                   // input row -1 is zero pad
    const bool bot = (y0 == H - RPW);             // input row H is zero pad

    // clamped row pointers for the 6 input rows (pad rows zeroed after load)
    const float* rp[NRW];
#pragma unroll
    for (int s = 0; s < NRW; ++s) {
        int y = y0 - 1 + s;
        y = y < 0 ? 0 : (y > H - 1 ? H - 1 : y);
        rp[s] = base + ((size_t)y << 10);
    }

    const int xo = lane << 2;                     // 4 px per lane per chunk

    v4f   c[2][NRW];                              // double-buffered chunk regs
    float carry[NRW];                             // left halo from prev chunk
#pragma unroll
    for (int s = 0; s < NRW; ++s) carry[s] = 0.0f;   // image left edge -> 0

    // ---- load chunk 0 (6 coalesced dwordx4)
#pragma unroll
    for (int s = 0; s < NRW; ++s)
        c[0][s] = *reinterpret_cast<const v4f*>(rp[s] + xo);
    if (top) c[0][0]       = (v4f){0.0f, 0.0f, 0.0f, 0.0f};
    if (bot) c[0][NRW - 1] = (v4f){0.0f, 0.0f, 0.0f, 0.0f};

    // ---- 4 column-chunks of 256 px; j fully unrolled (compile-time indices)
#pragma unroll
    for (int j = 0; j < 4; ++j) {
        const int cur = j & 1, nxt = cur ^ 1;
        if (j < 3) {                              // load next chunk (prefetch)
#pragma unroll
            for (int s = 0; s < NRW; ++s)
                c[nxt][s] = *reinterpret_cast<const v4f*>(rp[s] + ((j + 1) << 8) + xo);
            if (top) c[nxt][0]       = (v4f){0.0f, 0.0f, 0.0f, 0.0f};
            if (bot) c[nxt][NRW - 1] = (v4f){0.0f, 0.0f, 0.0f, 0.0f};
        }

        // halos for the 6 rows of this chunk (all in-register)
        float hl[NRW], hr[NRW];
#pragma unroll
        for (int s = 0; s < NRW; ++s) {
            const float u  = __shfl_up(c[cur][s].w, 1);
            hl[s] = (lane == 0) ? carry[s] : u;                    // px j*256+4L-1
            const float d  = __shfl_down(c[cur][s].x, 1);
            const float nb = (j < 3) ? __shfl(c[nxt][s].x, 0) : 0.0f; // img right edge
            hr[s] = (lane == 63) ? nb : d;                         // px j*256+4L+4
            carry[s] = __shfl(c[cur][s].w, 63);                    // for next chunk
        }

        // 4 output rows: vertical sort3 per column + med3-of-candidates
#pragma unroll
        for (int r = 0; r < RPW; ++r) {
            const float t[6] = { hl[r],     c[cur][r].x,     c[cur][r].y,     c[cur][r].z,     c[cur][r].w,     hr[r]     };
            const float m[6] = { hl[r + 1], c[cur][r + 1].x, c[cur][r + 1].y, c[cur][r + 1].z, c[cur][r + 1].w, hr[r + 1] };
            const float b[6] = { hl[r + 2], c[cur][r + 2].x, c[cur][r + 2].y, c[cur][r + 2].z, c[cur][r + 2].w, hr[r + 2] };

            float lo[6], mi[6], hi[6];
#pragma unroll
            for (int q = 0; q < 6; ++q) {
                float a = t[q], c0 = m[q], d = b[q];
                S2(a, c0); S2(c0, d); S2(a, c0);
                lo[q] = a; mi[q] = c0; hi[q] = d;
            }
            v4f o;
#pragma unroll
            for (int q = 0; q < 4; ++q) {
                const float mxlo = fmaxf(lo[q], fmaxf(lo[q + 1], lo[q + 2]));
                const float mnhi = fminf(hi[q], fminf(hi[q + 1], hi[q + 2]));
                const float mdmi = med3f(mi[q], mi[q + 1], mi[q + 2]);
                const float med  = med3f(mxlo, mdmi, mnhi);
                const float xc   = m[q + 1];
                o[q] = xc + 0.2f * (med - xc);
            }
            *reinterpret_cast<v4f*>(obase + ((size_t)(y0 + r) << 10) + (j << 8) + xo) = o;
        }
    }
}

extern "C" void kernel_launch(void* const* d_in, const int* in_sizes, int n_in,
                              void* d_out, int out_size, void* d_ws, size_t ws_size,
                              hipStream_t stream) {
    const float* x = (const float*)d_in[0];
    float* out = (float*)d_out;
    const int planes = in_sizes[0] / (H * W);     // 24
    dim3 block(256);
    dim3 grid(planes * (H / 16));                 // 1536 blocks (16 rows/block), %8==0
    median_blur_kernel<<<grid, block, 0, stream>>>(x, out);
}